// Round 20
// baseline (35.116 us; speedup 1.0000x reference)
//
#include <hip/hip_runtime.h>
#include <hip/hip_bf16.h>
#include <hip/hip_fp16.h>

// Problem: B=N=1024, in_f=1024, OUT_F=32, KD=8
// out[n][0:1024]   = x[n][:]
// M[n][o*8+k]      = sum_f x[n][f] * T[f][o*8+k]        (T flat [1024][256])
// out[n][1024+o]   = sum_{i != n} exp(-sum_k |M[i][o*8+k] - M[n][o*8+k]|)
//
// R19: TWO nodes. gemm_full (full-K in-register, 64 blocks x 512 thr) writes
// transposed f16 Mt*log2e directly (part+reduce deleted); pairwise13 (R16
// best) absorbs the x->out copy. Pairwise asm experiment reverted (R18: the
// loop is latency-bound; asm serialization == compiler's fat-but-pipelined).

#define N_ROWS 1024
#define IN_F   1024
#define OUT_C  1056
#define OK     256   // OUT_F*KD
#define KC     128   // K-chunk (LDS-sized)
#define LOG2E  1.44269504f

typedef __attribute__((ext_vector_type(8))) short bf16x8;
typedef __attribute__((ext_vector_type(4))) float f32x4;
typedef _Float16 hv2 __attribute__((ext_vector_type(2)));

__device__ __forceinline__ float fast_exp2(float x) {
#if __has_builtin(__builtin_amdgcn_exp2f)
  return __builtin_amdgcn_exp2f(x);   // v_exp_f32 = 2^x
#else
  return __expf(x * 0.6931472f);
#endif
}

// packed |.| on an f16 pair: single v_and_b32
__device__ __forceinline__ hv2 habs2v(hv2 v) {
  unsigned u = __builtin_bit_cast(unsigned, v) & 0x7fff7fffu;
  return __builtin_bit_cast(hv2, u);
}

// RNE pack of two f32 -> u32 of 2 bf16 (lo = a, hi = b)
__device__ __forceinline__ unsigned cvt_pk_bf16(float a, float b) {
  unsigned r;
  asm("v_cvt_pk_bf16_f32 %0, %1, %2" : "=v"(r) : "v"(a), "v"(b));
  return r;
}

union HQ { uint4 q; hv2 h[4]; };

// ---------------- kernel 1: full-K bf16 MFMA GEMM -> f16 Mt ------------------
// grid (16 m, 4 n) = 64 blocks x 512 thr (8 waves). Loops 8 K-chunks:
// stage f32->bf16 (cvt_pk, XOR-swizzled LDS) + MFMA, acc in registers.
// Wave w: rows (w&3)*16, cols (w>>2)*32 (2 n-tiles). Epilogue: Mt[o][n][k].
__global__ __launch_bounds__(512) void gemm_full_kernel(
    const float* __restrict__ x,   // [1024][1024] f32
    const float* __restrict__ T,   // [1024][256] f32
    __half* __restrict__ Mt) {     // [32][1024][8] f16, *log2e
  __shared__ unsigned short asw[64 * 128];  // A tile, XOR-swizzled
  __shared__ unsigned short bsw[64 * 128];  // B tile (col-major via transpose)
  const int m0 = blockIdx.x * 64;
  const int n0 = blockIdx.y * 64;
  const int t  = threadIdx.x;

  const int l  = t & 63, w = t >> 6;        // lane, wave (0..7)
  const int lr = l & 15, lg = l >> 4;
  const int arow = (w & 3) * 16 + lr;
  const int aswz = arow & 15;               // == lr
  const int cb   = (w >> 2) * 32;           // wave's col base (0 or 32)

  f32x4 acc0 = {0.f, 0.f, 0.f, 0.f};
  f32x4 acc1 = {0.f, 0.f, 0.f, 0.f};

  for (int ks = 0; ks < 8; ++ks) {
    const int k0 = ks * KC;
    // stage A: 64 rows x 32 float4 = 2048 f4, 4/thread
#pragma unroll
    for (int u = 0; u < 4; ++u) {
      int idx = u * 512 + t;
      int row = idx >> 5, fk = idx & 31;
      float4 v = *reinterpret_cast<const float4*>(
          x + (size_t)(m0 + row) * IN_F + k0 + fk * 4);
      unsigned lo = cvt_pk_bf16(v.x, v.y);
      unsigned hi = cvt_pk_bf16(v.z, v.w);
      int slot = fk >> 1, half = fk & 1;
      unsigned short* dst = asw + row * 128 + ((slot ^ (row & 15)) * 8) + half * 4;
      *reinterpret_cast<uint2*>(dst) = make_uint2(lo, hi);
    }
    // stage B (transpose): 2048 units of (2 cols x 2 ks), 4/thread
#pragma unroll
    for (int u = 0; u < 4; ++u) {
      int w2 = u * 512 + t;
      int c = (w2 & 31) * 2, kk = (w2 >> 5) * 2;
      const float* Tp = T + (size_t)(k0 + kk) * OK + n0 + c;
      float2 v0 = *reinterpret_cast<const float2*>(Tp);
      float2 v1 = *reinterpret_cast<const float2*>(Tp + OK);
      unsigned p0 = cvt_pk_bf16(v0.x, v1.x);
      unsigned p1 = cvt_pk_bf16(v0.y, v1.y);
      int slot = kk >> 3, sub = kk & 7;
      *reinterpret_cast<unsigned*>(
          bsw + (c) * 128 + ((slot ^ (c & 15)) * 8) + sub) = p0;
      *reinterpret_cast<unsigned*>(
          bsw + (c + 1) * 128 + ((slot ^ ((c + 1) & 15)) * 8) + sub) = p1;
    }
    __syncthreads();

#pragma unroll
    for (int kk = 0; kk < 4; ++kk) {
      int slotA = kk * 4 + lg;
      bf16x8 a = *reinterpret_cast<const bf16x8*>(
          asw + arow * 128 + ((slotA ^ aswz) * 8));
      int sb = (slotA ^ lr) * 8;
      bf16x8 b0 = *reinterpret_cast<const bf16x8*>(bsw + (cb + lr)      * 128 + sb);
      bf16x8 b1 = *reinterpret_cast<const bf16x8*>(bsw + (cb + 16 + lr) * 128 + sb);
      acc0 = __builtin_amdgcn_mfma_f32_16x16x32_bf16(a, b0, acc0, 0, 0, 0);
      acc1 = __builtin_amdgcn_mfma_f32_16x16x32_bf16(a, b1, acc1, 0, 0, 0);
    }
    __syncthreads();   // LDS reused next chunk
  }

  // epilogue: C/D layout col = lane&15 (within 16-tile), row = lg*4 + r.
  // Mt[o][n][k]: o = col>>3, k = col&7.
#pragma unroll
  for (int nt = 0; nt < 2; ++nt) {
    int col = n0 + cb + nt * 16 + lr;
    int o = col >> 3, k = col & 7;
    f32x4 a = nt ? acc1 : acc0;
#pragma unroll
    for (int r = 0; r < 4; ++r) {
      int row = m0 + (w & 3) * 16 + lg * 4 + r;
      Mt[(size_t)o * (N_ROWS * 8) + row * 8 + k] = __float2half(a[r] * LOG2E);
    }
  }
}

// ---------------- kernel 2: pairwise exp2(-L1) v13 + fused x->out copy -------
// grid (o:32, jt:16) = 512 blocks x 256 thr. Stage contiguous 16 KB Mt[o]
// slice; ONE ds_read_b128/i; packed-f16 tree (compiler-scheduled — R18 showed
// it pipelines across the unroll better than atomic asm blocks). Each block
// also copies 512 float4 of x -> out (overlaps with LDS compute).
__global__ __launch_bounds__(256) void pairwise13_kernel(
    const __half* __restrict__ Mt, const float* __restrict__ x,
    float* __restrict__ out) {
  __shared__ uint4 sm[N_ROWS];      // 16 KB: row n = 8 halves of Mt[o][n][:]
  __shared__ float red[4][64];

  int o  = blockIdx.x;
  int jt = blockIdx.y;
  int t  = threadIdx.x;
  int b  = blockIdx.y * 32 + blockIdx.x;   // 0..511 flat for the copy

  const uint4* src = reinterpret_cast<const uint4*>(Mt + (size_t)o * (N_ROWS * 8));
#pragma unroll
  for (int u = 0; u < 4; ++u)
    sm[t + 256 * u] = src[t + 256 * u];

  // fused copy: 512 f4 per block (independent of LDS path)
#pragma unroll
  for (int u = 0; u < 2; ++u) {
    int idx = b * 512 + u * 256 + t;
    int row = idx >> 8, col4 = idx & 255;
    float4 v = *reinterpret_cast<const float4*>(x + (size_t)row * IN_F + col4 * 4);
    *reinterpret_cast<float4*>(out + (size_t)row * OUT_C + col4 * 4) = v;
  }
  __syncthreads();

  int jl = t & 63, s = t >> 6;
  int j  = jt * 64 + jl;

  HQ ju; ju.q = sm[j];
  hv2 r0 = ju.h[0], r1 = ju.h[1], r2 = ju.h[2], r3 = ju.h[3];

  float acc = 0.f;
  const uint4* base = &sm[s * 256];
#pragma unroll 8
  for (int i = 0; i < 256; ++i) {
    HQ u_; u_.q = base[i];              // one ds_read_b128
    hv2 d2 = (habs2v(u_.h[0] - r0) + habs2v(u_.h[1] - r1)) +
             (habs2v(u_.h[2] - r2) + habs2v(u_.h[3] - r3));
    float d = (float)(d2.x + d2.y);
    acc += fast_exp2(-d);               // large d underflows to 0
  }
  if ((j >> 8) == s) acc -= 1.0f;       // exact self term exp2(0)=1

  red[s][jl] = acc;
  __syncthreads();

  if (t < 64) {
    float v = red[0][t] + red[1][t] + red[2][t] + red[3][t];
    int jj = jt * 64 + t;
    out[(size_t)jj * OUT_C + 1024 + o] = v;
  }
}

// ---------------- fallback path (small ws): f32 single-pass ------------------
#define BK 16
__global__ __launch_bounds__(256) void gemm32_kernel(
    const float* __restrict__ A, const float* __restrict__ Bm, float* __restrict__ M) {
  __shared__ float as2[BK][32];
  __shared__ float bs2[BK][32];
  int m0 = blockIdx.x * 32;
  int n0 = blockIdx.y * 32;
  int t  = threadIdx.x;
  int ty = t >> 4, tx = t & 15;
  float c00 = 0.f, c01 = 0.f, c10 = 0.f, c11 = 0.f;
  for (int k0 = 0; k0 < IN_F; k0 += BK) {
    if (t < 128) {
      int row = t >> 2, q = t & 3;
      float4 v = *reinterpret_cast<const float4*>(A + (size_t)(m0 + row) * IN_F + k0 + q * 4);
      as2[q * 4 + 0][row] = v.x; as2[q * 4 + 1][row] = v.y;
      as2[q * 4 + 2][row] = v.z; as2[q * 4 + 3][row] = v.w;
    } else {
      int tt = t - 128;
      int row = tt >> 3, q = tt & 7;
      float4 v = *reinterpret_cast<const float4*>(Bm + (size_t)(k0 + row) * OK + n0 + q * 4);
      *reinterpret_cast<float4*>(&bs2[row][q * 4]) = v;
    }
    __syncthreads();
#pragma unroll
    for (int kk = 0; kk < BK; ++kk) {
      float2 a = *reinterpret_cast<const float2*>(&as2[kk][ty * 2]);
      float2 b = *reinterpret_cast<const float2*>(&bs2[kk][tx * 2]);
      c00 += a.x * b.x; c01 += a.x * b.y;
      c10 += a.y * b.x; c11 += a.y * b.y;
    }
    __syncthreads();
  }
  int r = m0 + ty * 2, c = n0 + tx * 2;
  M[(size_t)r * OK + c]           = c00 * LOG2E;
  M[(size_t)r * OK + c + 1]       = c01 * LOG2E;
  M[(size_t)(r + 1) * OK + c]     = c10 * LOG2E;
  M[(size_t)(r + 1) * OK + c + 1] = c11 * LOG2E;
}

__global__ __launch_bounds__(256) void pairwise_kernel(
    const float* __restrict__ M, float* __restrict__ out) {
  __shared__ float sm[N_ROWS][8];
  __shared__ float red[4][64];
  int o  = blockIdx.x;
  int jt = blockIdx.y;
  int t  = threadIdx.x;
#pragma unroll
  for (int idx = t; idx < 2048; idx += 256) {
    int row = idx >> 1, half = idx & 1;
    *reinterpret_cast<float4*>(&sm[row][half * 4]) =
        *reinterpret_cast<const float4*>(M + (size_t)row * OK + o * 8 + half * 4);
  }
  __syncthreads();
  int jl = t & 63, s = t >> 6;
  int j  = jt * 64 + jl;
  float4 ra = *reinterpret_cast<const float4*>(&sm[j][0]);
  float4 rb = *reinterpret_cast<const float4*>(&sm[j][4]);
  float acc = 0.f;
  const float* base = &sm[s * 256][0];
#pragma unroll 4
  for (int i = 0; i < 256; ++i) {
    float4 va = *reinterpret_cast<const float4*>(base + i * 8);
    float4 vb = *reinterpret_cast<const float4*>(base + i * 8 + 4);
    float d = fabsf(va.x - ra.x) + fabsf(va.y - ra.y) +
              fabsf(va.z - ra.z) + fabsf(va.w - ra.w) +
              fabsf(vb.x - rb.x) + fabsf(vb.y - rb.y) +
              fabsf(vb.z - rb.z) + fabsf(vb.w - rb.w);
    acc += fast_exp2(-d);
  }
  if ((j >> 8) == s) acc -= 1.0f;
  red[s][jl] = acc;
  __syncthreads();
  if (t < 64) {
    float v = red[0][t] + red[1][t] + red[2][t] + red[3][t];
    int jj = jt * 64 + t;
    out[(size_t)jj * OUT_C + 1024 + o] = v;
  }
}

__global__ __launch_bounds__(256) void copy_x_kernel(
    const float* __restrict__ x, float* __restrict__ out) {
  int n = blockIdx.x;
  int c = threadIdx.x * 4;
  float4 v = *reinterpret_cast<const float4*>(x + (size_t)n * IN_F + c);
  *reinterpret_cast<float4*>(out + (size_t)n * OUT_C + c) = v;
}

extern "C" void kernel_launch(void* const* d_in, const int* in_sizes, int n_in,
                              void* d_out, int out_size, void* d_ws, size_t ws_size,
                              hipStream_t stream) {
  const float* x = (const float*)d_in[0];   // [1024][1024]
  const float* T = (const float*)d_in[1];   // [1024][256]
  float* out = (float*)d_out;               // [1024][1056]

  const size_t mElems = (size_t)N_ROWS * OK;   // 262144
  const size_t needed = mElems * 2;            // Mt 0.5 MB

  if (ws_size >= needed) {
    __half* Mt = (__half*)d_ws;
    gemm_full_kernel<<<dim3(16, 4), dim3(512), 0, stream>>>(x, T, Mt);
    pairwise13_kernel<<<dim3(32, 16), dim3(256), 0, stream>>>(Mt, x, out);
  } else {
    float* M = (float*)d_ws;
    copy_x_kernel<<<dim3(N_ROWS), dim3(256), 0, stream>>>(x, out);
    gemm32_kernel<<<dim3(32, 8), dim3(256), 0, stream>>>(x, T, M);
    pairwise_kernel<<<dim3(32, 16), dim3(256), 0, stream>>>(M, out);
  }
}